// Round 4
// baseline (24.041 us; speedup 1.0000x reference)
//
#include <hip/hip_runtime.h>
#include <math.h>

#define NB 8
#define ND 256        // sequence length
#define NN 64         // channels (head_dim = 1)
#define IQ 4          // i-split: blocks per (b,n)
#define ROWS (ND/IQ)  // 64 output rows per block
#define KST 20        // padded LDS stride (floats) for 16-float j-slices

// Grid = 2048 blocks: (b,n) x i-quarter. Per block:
//  - projection: thread t computes q,k,v for row t (W read via wave-uniform
//    scalar loads -> SGPRs, no LDS for W)
//  - k,v stored in padded [16][20] LDS slices; q (pre-scaled) in qs[256]
//  - softmax: thread (rs,jg) = 4 rows x 16 j; k/v float4 reused across 4 rows
//  - partials reduced across the 16 jg-lanes via __shfl_xor (no 2nd barrier)
__global__ __launch_bounds__(256, 6)
void fused_mhsa_kernel(const float* __restrict__ x,
                       const float* __restrict__ W,
                       float* __restrict__ out) {
    const int bid = blockIdx.x;       // 0..2047
    const int bn  = bid >> 2;         // (b,n)
    const int iq  = bid & 3;          // which 64-row window
    const int b   = bn >> 6;
    const int n   = bn & 63;
    const int t   = threadIdx.x;      // 0..255

    __shared__ __align__(16) float qs[ND];
    __shared__ __align__(16) float ks2[16][KST];
    __shared__ __align__(16) float vs2[16][KST];
    __shared__ float red[8];

    // ---- projection: thread t -> row t; W via uniform scalar loads ----
    const float4* xrow = reinterpret_cast<const float4*>(x + ((size_t)b * ND + t) * NN);
    const float* Wc = W + n;          // block-uniform base; cols n, n+64, n+128
    float q = 0.f, k = 0.f, v = 0.f;
    #pragma unroll
    for (int m4 = 0; m4 < NN / 4; ++m4) {
        const float4 xv = xrow[m4];
        const int m = m4 * 4;
        q = fmaf(xv.x, Wc[(m+0)*192 +   0], q);
        k = fmaf(xv.x, Wc[(m+0)*192 +  64], k);
        v = fmaf(xv.x, Wc[(m+0)*192 + 128], v);
        q = fmaf(xv.y, Wc[(m+1)*192 +   0], q);
        k = fmaf(xv.y, Wc[(m+1)*192 +  64], k);
        v = fmaf(xv.y, Wc[(m+1)*192 + 128], v);
        q = fmaf(xv.z, Wc[(m+2)*192 +   0], q);
        k = fmaf(xv.z, Wc[(m+2)*192 +  64], k);
        v = fmaf(xv.z, Wc[(m+2)*192 + 128], v);
        q = fmaf(xv.w, Wc[(m+3)*192 +   0], q);
        k = fmaf(xv.w, Wc[(m+3)*192 +  64], k);
        v = fmaf(xv.w, Wc[(m+3)*192 + 128], v);
    }
    const float LOG2E = 1.4426950408889634f;
    qs[t] = q * (0.125f * LOG2E);     // pre-scaled: exponent = qs*k - m2 (log2)
    ks2[t >> 4][t & 15] = k;
    vs2[t >> 4][t & 15] = v;

    // ---- block reduce kmax/kmin (rank-1 scores: row max = qs*kmax|qs*kmin) ----
    float kmax = k, kmin = k;
    #pragma unroll
    for (int off = 32; off > 0; off >>= 1) {
        kmax = fmaxf(kmax, __shfl_xor(kmax, off));
        kmin = fminf(kmin, __shfl_xor(kmin, off));
    }
    const int wave = t >> 6;
    if ((t & 63) == 0) { red[wave] = kmax; red[4 + wave] = kmin; }
    __syncthreads();                  // the only barrier
    kmax = fmaxf(fmaxf(red[0], red[1]), fmaxf(red[2], red[3]));
    kmin = fminf(fminf(red[4], red[5]), fminf(red[6], red[7]));

    // ---- softmax: thread = (rs: 4 rows) x (jg: 16 j-values) ----
    const int jg = t & 15;
    const int rs = t >> 4;            // 0..15

    const float4 q4 = *reinterpret_cast<const float4*>(&qs[iq * ROWS + rs * 4]);
    const float qm0 = q4.x, qm1 = q4.y, qm2 = q4.z, qm3 = q4.w;
    const float nm0 = -fmaxf(qm0 * kmax, qm0 * kmin);
    const float nm1 = -fmaxf(qm1 * kmax, qm1 * kmin);
    const float nm2 = -fmaxf(qm2 * kmax, qm2 * kmin);
    const float nm3 = -fmaxf(qm3 * kmax, qm3 * kmin);

    float s0 = 0.f, s1 = 0.f, s2 = 0.f, s3 = 0.f;
    float a0 = 0.f, a1 = 0.f, a2 = 0.f, a3 = 0.f;
    #pragma unroll
    for (int c = 0; c < 4; ++c) {
        const float4 kc = *reinterpret_cast<const float4*>(&ks2[jg][c * 4]);
        const float4 vc = *reinterpret_cast<const float4*>(&vs2[jg][c * 4]);
        float e;
        e = __builtin_amdgcn_exp2f(fmaf(qm0, kc.x, nm0)); s0 += e; a0 = fmaf(e, vc.x, a0);
        e = __builtin_amdgcn_exp2f(fmaf(qm0, kc.y, nm0)); s0 += e; a0 = fmaf(e, vc.y, a0);
        e = __builtin_amdgcn_exp2f(fmaf(qm0, kc.z, nm0)); s0 += e; a0 = fmaf(e, vc.z, a0);
        e = __builtin_amdgcn_exp2f(fmaf(qm0, kc.w, nm0)); s0 += e; a0 = fmaf(e, vc.w, a0);
        e = __builtin_amdgcn_exp2f(fmaf(qm1, kc.x, nm1)); s1 += e; a1 = fmaf(e, vc.x, a1);
        e = __builtin_amdgcn_exp2f(fmaf(qm1, kc.y, nm1)); s1 += e; a1 = fmaf(e, vc.y, a1);
        e = __builtin_amdgcn_exp2f(fmaf(qm1, kc.z, nm1)); s1 += e; a1 = fmaf(e, vc.z, a1);
        e = __builtin_amdgcn_exp2f(fmaf(qm1, kc.w, nm1)); s1 += e; a1 = fmaf(e, vc.w, a1);
        e = __builtin_amdgcn_exp2f(fmaf(qm2, kc.x, nm2)); s2 += e; a2 = fmaf(e, vc.x, a2);
        e = __builtin_amdgcn_exp2f(fmaf(qm2, kc.y, nm2)); s2 += e; a2 = fmaf(e, vc.y, a2);
        e = __builtin_amdgcn_exp2f(fmaf(qm2, kc.z, nm2)); s2 += e; a2 = fmaf(e, vc.z, a2);
        e = __builtin_amdgcn_exp2f(fmaf(qm2, kc.w, nm2)); s2 += e; a2 = fmaf(e, vc.w, a2);
        e = __builtin_amdgcn_exp2f(fmaf(qm3, kc.x, nm3)); s3 += e; a3 = fmaf(e, vc.x, a3);
        e = __builtin_amdgcn_exp2f(fmaf(qm3, kc.y, nm3)); s3 += e; a3 = fmaf(e, vc.y, a3);
        e = __builtin_amdgcn_exp2f(fmaf(qm3, kc.z, nm3)); s3 += e; a3 = fmaf(e, vc.z, a3);
        e = __builtin_amdgcn_exp2f(fmaf(qm3, kc.w, nm3)); s3 += e; a3 = fmaf(e, vc.w, a3);
    }

    // ---- reduce partials across the 16 jg-lanes (within-wave, no barrier) ----
    #pragma unroll
    for (int off = 1; off < 16; off <<= 1) {
        s0 += __shfl_xor(s0, off); a0 += __shfl_xor(a0, off);
        s1 += __shfl_xor(s1, off); a1 += __shfl_xor(a1, off);
        s2 += __shfl_xor(s2, off); a2 += __shfl_xor(a2, off);
        s3 += __shfl_xor(s3, off); a3 += __shfl_xor(a3, off);
    }

    if (jg < 4) {
        const float av = (jg == 0) ? a0 : (jg == 1) ? a1 : (jg == 2) ? a2 : a3;
        const float sv = (jg == 0) ? s0 : (jg == 1) ? s1 : (jg == 2) ? s2 : s3;
        const int row = iq * ROWS + rs * 4 + jg;
        out[((size_t)b * ND + row) * NN + n] = av / sv;
    }
}

extern "C" void kernel_launch(void* const* d_in, const int* in_sizes, int n_in,
                              void* d_out, int out_size, void* d_ws, size_t ws_size,
                              hipStream_t stream) {
    const float* x = (const float*)d_in[0];   // (8, 256, 64) fp32
    const float* W = (const float*)d_in[1];   // (64, 192) fp32
    float* out = (float*)d_out;               // (8, 256, 64) fp32

    dim3 grid(NB * NN * IQ);   // 2048 blocks
    dim3 block(ND);            // 256 threads
    fused_mhsa_kernel<<<grid, block, 0, stream>>>(x, W, out);
}

// Round 5
// 15.179 us; speedup vs baseline: 1.5838x; 1.5838x over previous
//
#include <hip/hip_runtime.h>
#include <math.h>

#define NB 8
#define ND 256        // sequence length
#define NN 64         // channels (head_dim = 1)
#define NT 512        // threads per block
#define JH 128        // j-values per thread (half of ND)

// One block per (b,n), 512 threads = (row i = t&255) x (j-half h = t>>8).
// Projection (q,k,v per row) by waves 0-3 only; softmax j-loop split in half
// across h so all 8 waves work the dominant phase; h=1 partials combine via
// 2 KB LDS + one barrier.
__global__ __launch_bounds__(NT, 4)
void fused_mhsa_kernel(const float* __restrict__ x,
                       const float* __restrict__ W,
                       float* __restrict__ out) {
    const int bn = blockIdx.x;        // 0..511
    const int b  = bn >> 6;
    const int n  = bn & 63;
    const int t  = threadIdx.x;       // 0..511
    const int i  = t & 255;           // sequence row
    const int h  = t >> 8;            // j-half 0..1

    __shared__ float wq[NN], wk[NN], wv[NN];
    __shared__ __align__(16) float qs[ND];
    __shared__ __align__(16) float ks[ND];
    __shared__ __align__(16) float vs[ND];
    __shared__ float red[8];          // kmax (0..3), kmin (4..7) from waves 0-3
    __shared__ float psum1[ND], pacc1[ND];

    // ---- stage the three W columns (n, 64+n, 128+n) into LDS ----
    if (t < 3 * NN) {
        const int which = t >> 6;     // 0:q 1:k 2:v
        const int m     = t & 63;
        const float val = W[m * (3 * NN) + which * NN + n];
        if (which == 0)      wq[m] = val;
        else if (which == 1) wk[m] = val;
        else                 wv[m] = val;
    }
    __syncthreads();

    // ---- projection: waves 0-3, thread t -> row t ----
    float k = 0.f;
    if (t < ND) {
        const float4* xrow = reinterpret_cast<const float4*>(x + ((size_t)b * ND + t) * NN);
        float q = 0.f, v = 0.f;
        #pragma unroll
        for (int m4 = 0; m4 < NN / 4; ++m4) {
            const float4 xv = xrow[m4];
            const int m = m4 * 4;
            q = fmaf(xv.x, wq[m+0], q); k = fmaf(xv.x, wk[m+0], k); v = fmaf(xv.x, wv[m+0], v);
            q = fmaf(xv.y, wq[m+1], q); k = fmaf(xv.y, wk[m+1], k); v = fmaf(xv.y, wv[m+1], v);
            q = fmaf(xv.z, wq[m+2], q); k = fmaf(xv.z, wk[m+2], k); v = fmaf(xv.z, wv[m+2], v);
            q = fmaf(xv.w, wq[m+3], q); k = fmaf(xv.w, wk[m+3], k); v = fmaf(xv.w, wv[m+3], v);
        }
        qs[t] = q * (0.125f * 1.4426950408889634f);  // pre-scaled log2-domain
        ks[t] = k;
        vs[t] = v;
    }

    // ---- kmax/kmin reduce (rank-1 scores: row max = qs*kmax | qs*kmin) ----
    float kmax = k, kmin = k;
    #pragma unroll
    for (int off = 32; off > 0; off >>= 1) {
        kmax = fmaxf(kmax, __shfl_xor(kmax, off));
        kmin = fminf(kmin, __shfl_xor(kmin, off));
    }
    if (t < ND && (t & 63) == 0) { red[t >> 6] = kmax; red[4 + (t >> 6)] = kmin; }
    __syncthreads();                  // publishes qs/ks/vs AND red
    kmax = fmaxf(fmaxf(red[0], red[1]), fmaxf(red[2], red[3]));
    kmin = fminf(fminf(red[4], red[5]), fminf(red[6], red[7]));

    // ---- softmax: row i over j in [h*128, h*128+128), 2 indep chains ----
    const float qv = qs[i];
    const float nm = -fmaxf(qv * kmax, qv * kmin);

    const float4* k4 = reinterpret_cast<const float4*>(ks) + h * (JH / 4);
    const float4* v4 = reinterpret_cast<const float4*>(vs) + h * (JH / 4);

    float sA = 0.f, sB = 0.f, aA = 0.f, aB = 0.f;
    #pragma unroll
    for (int jj = 0; jj < JH / 8; ++jj) {        // 16 iters, 8 j each
        const float4 ka = k4[jj * 2 + 0];
        const float4 kb = k4[jj * 2 + 1];
        const float4 va = v4[jj * 2 + 0];
        const float4 vb = v4[jj * 2 + 1];
        float e;
        e = __builtin_amdgcn_exp2f(fmaf(qv, ka.x, nm)); sA += e; aA = fmaf(e, va.x, aA);
        e = __builtin_amdgcn_exp2f(fmaf(qv, ka.y, nm)); sA += e; aA = fmaf(e, va.y, aA);
        e = __builtin_amdgcn_exp2f(fmaf(qv, ka.z, nm)); sA += e; aA = fmaf(e, va.z, aA);
        e = __builtin_amdgcn_exp2f(fmaf(qv, ka.w, nm)); sA += e; aA = fmaf(e, va.w, aA);
        e = __builtin_amdgcn_exp2f(fmaf(qv, kb.x, nm)); sB += e; aB = fmaf(e, vb.x, aB);
        e = __builtin_amdgcn_exp2f(fmaf(qv, kb.y, nm)); sB += e; aB = fmaf(e, vb.y, aB);
        e = __builtin_amdgcn_exp2f(fmaf(qv, kb.z, nm)); sB += e; aB = fmaf(e, vb.z, aB);
        e = __builtin_amdgcn_exp2f(fmaf(qv, kb.w, nm)); sB += e; aB = fmaf(e, vb.w, aB);
    }
    const float s = sA + sB;
    const float a = aA + aB;

    if (h == 1) { psum1[i] = s; pacc1[i] = a; }
    __syncthreads();

    // ---- combine halves and write (threads 0..255 are h==0 of row t) ----
    if (t < ND) {
        out[((size_t)b * ND + t) * NN + n] = (a + pacc1[t]) / (s + psum1[t]);
    }
}

extern "C" void kernel_launch(void* const* d_in, const int* in_sizes, int n_in,
                              void* d_out, int out_size, void* d_ws, size_t ws_size,
                              hipStream_t stream) {
    const float* x = (const float*)d_in[0];   // (8, 256, 64) fp32
    const float* W = (const float*)d_in[1];   // (64, 192) fp32
    float* out = (float*)d_out;               // (8, 256, 64) fp32

    dim3 grid(NB * NN);   // 512 blocks, one per (b, n)
    dim3 block(NT);       // 512 threads
    fused_mhsa_kernel<<<grid, block, 0, stream>>>(x, W, out);
}